// Round 2
// baseline (476.514 us; speedup 1.0000x reference)
//
#include <hip/hip_runtime.h>
#include <stdint.h>

#define TSEQ 1024
#define DDIM 512

typedef __attribute__((ext_vector_type(8))) short bf16x8;
typedef __attribute__((ext_vector_type(4))) float f32x4;

#define MFMA(a, b, c) __builtin_amdgcn_mfma_f32_16x16x32_bf16((a), (b), (c), 0, 0, 0)

__device__ __forceinline__ unsigned short f2bf(float f) {
  unsigned int u = __builtin_bit_cast(unsigned int, f);
  u += 0x7FFFu + ((u >> 16) & 1u);
  return (unsigned short)(u >> 16);
}

__device__ __forceinline__ void async_load16(const void* g, void* l) {
  __builtin_amdgcn_global_load_lds(
      (const __attribute__((address_space(1))) unsigned int*)g,
      (__attribute__((address_space(3))) unsigned int*)l, 16, 0, 0);
}

// ---------------- LayerNorm: x[65536][512] f32 -> nx bf16 ----------------
__global__ __launch_bounds__(256) void k_ln(const float* __restrict__ x,
                                            const float* __restrict__ gamma,
                                            const float* __restrict__ beta,
                                            unsigned short* __restrict__ nx) {
  const int wid = threadIdx.x >> 6, lane = threadIdx.x & 63;
  const long long row = (long long)blockIdx.x * 4 + wid;
  const float* xr = x + row * DDIM + lane * 8;
  float4 a = *(const float4*)xr;
  float4 b = *(const float4*)(xr + 4);
  float s = a.x + a.y + a.z + a.w + b.x + b.y + b.z + b.w;
  float s2 = a.x * a.x + a.y * a.y + a.z * a.z + a.w * a.w +
             b.x * b.x + b.y * b.y + b.z * b.z + b.w * b.w;
#pragma unroll
  for (int m = 1; m < 64; m <<= 1) {
    s += __shfl_xor(s, m);
    s2 += __shfl_xor(s2, m);
  }
  const float mu = s * (1.0f / DDIM);
  const float var = s2 * (1.0f / DDIM) - mu * mu;
  const float rsd = rsqrtf(var + 1e-5f);
  const float4 g0 = *(const float4*)(gamma + lane * 8);
  const float4 g1 = *(const float4*)(gamma + lane * 8 + 4);
  const float4 b0 = *(const float4*)(beta + lane * 8);
  const float4 b1 = *(const float4*)(beta + lane * 8 + 4);
  float o0 = (a.x - mu) * rsd * g0.x + b0.x;
  float o1 = (a.y - mu) * rsd * g0.y + b0.y;
  float o2 = (a.z - mu) * rsd * g0.z + b0.z;
  float o3 = (a.w - mu) * rsd * g0.w + b0.w;
  float o4 = (b.x - mu) * rsd * g1.x + b1.x;
  float o5 = (b.y - mu) * rsd * g1.y + b1.y;
  float o6 = (b.z - mu) * rsd * g1.z + b1.z;
  float o7 = (b.w - mu) * rsd * g1.w + b1.w;
  uint4 pk;
  pk.x = f2bf(o0) | ((unsigned)f2bf(o1) << 16);
  pk.y = f2bf(o2) | ((unsigned)f2bf(o3) << 16);
  pk.z = f2bf(o4) | ((unsigned)f2bf(o5) << 16);
  pk.w = f2bf(o6) | ((unsigned)f2bf(o7) << 16);
  *(uint4*)(nx + row * DDIM + lane * 8) = pk;
}

// ---------------- cast Wg f32 -> bf16 ----------------
__global__ __launch_bounds__(256) void k_cast(const float* __restrict__ w,
                                              unsigned short* __restrict__ o, int n8) {
  const int i = blockIdx.x * 256 + threadIdx.x;
  if (i >= n8) return;
  const float4 a = *(const float4*)(w + (size_t)i * 8);
  const float4 b = *(const float4*)(w + (size_t)i * 8 + 4);
  uint4 pk;
  pk.x = f2bf(a.x) | ((unsigned)f2bf(a.y) << 16);
  pk.y = f2bf(a.z) | ((unsigned)f2bf(a.w) << 16);
  pk.z = f2bf(b.x) | ((unsigned)f2bf(b.y) << 16);
  pk.w = f2bf(b.z) | ((unsigned)f2bf(b.w) << 16);
  *(uint4*)(o + (size_t)i * 8) = pk;
}

// ---------------- GEMM: qkv[M][512] = nx[M][512] @ Wg[512][512]^T ----------
// m97 structure: 128x128 tile, BK=64, 4 waves (2x2), LINEAR LDS (no swizzle),
// global_load_lds width=16, ds_read_b128 fragments.
__global__ __launch_bounds__(256, 2) void k_gemm(const unsigned short* __restrict__ A,
                                                 const unsigned short* __restrict__ B,
                                                 unsigned short* __restrict__ C) {
  __shared__ char As[16384];
  __shared__ char Bs[16384];
  const int tid = threadIdx.x;
  const int wid = tid >> 6, lane = tid & 63;
  const int g = lane >> 4, c = lane & 15;
  const int wr = wid >> 1, wc = wid & 1;
  const int bm = blockIdx.y, bn = blockIdx.x;

  int srcoff[4], ldsoff[4];
#pragma unroll
  for (int r = 0; r < 4; ++r) {
    const int aoff = r * 4096 + tid * 16;           // linear LDS byte addr
    srcoff[r] = (aoff >> 7) * 1024 + (aoff & 127);  // global: row*1024 + col bytes
    ldsoff[r] = r * 4096 + (wid << 10);             // wave-uniform base
  }
  const char* Ab = (const char*)A + (size_t)bm * 131072;
  const char* Bb = (const char*)B + (size_t)bn * 131072;

  f32x4 acc[4][4] = {};

  for (int ks = 0; ks < 8; ++ks) {
    __syncthreads();
#pragma unroll
    for (int r = 0; r < 4; ++r) {
      async_load16(Ab + ks * 128 + srcoff[r], As + ldsoff[r]);
      async_load16(Bb + ks * 128 + srcoff[r], Bs + ldsoff[r]);
    }
    __syncthreads();
    bf16x8 af[4][2], bfr[4][2];
#pragma unroll
    for (int f = 0; f < 4; ++f) {
#pragma unroll
      for (int kk = 0; kk < 2; ++kk) {
        const int rowa = wr * 64 + f * 16 + c;
        af[f][kk] = *(const bf16x8*)(As + rowa * 128 + (kk * 4 + g) * 16);
        const int rowb = wc * 64 + f * 16 + c;
        bfr[f][kk] = *(const bf16x8*)(Bs + rowb * 128 + (kk * 4 + g) * 16);
      }
    }
#pragma unroll
    for (int i = 0; i < 4; ++i) {
#pragma unroll
      for (int j = 0; j < 4; ++j) {
        acc[i][j] = MFMA(af[i][0], bfr[j][0], acc[i][j]);
        acc[i][j] = MFMA(af[i][1], bfr[j][1], acc[i][j]);
      }
    }
  }
#pragma unroll
  for (int i = 0; i < 4; ++i) {
#pragma unroll
    for (int r = 0; r < 4; ++r) {
      const long long row = (long long)bm * 128 + wr * 64 + i * 16 + g * 4 + r;
#pragma unroll
      for (int j = 0; j < 4; ++j) {
        const int col = bn * 128 + wc * 64 + j * 16 + c;
        C[row * DDIM + col] = f2bf(acc[i][j][r]);
      }
    }
  }
}

// ---------------- Flash attention (causal), Q=K=V=qkv, + residual add --------
// SAFE version: linear KV LDS [64][512] bf16 (contiguous copy), linear K-frag
// reads (conflicted but correct), V-frags via strided ds_read_u16 (no tr_read).
// Swapped QK^T: st = mfma(K, Q^T) -> lane holds S[q = c][16 kv vals].
__global__ __launch_bounds__(512, 2) void k_attn(const unsigned short* __restrict__ qkv,
                                                 const float* __restrict__ x,
                                                 float* __restrict__ xo) {
  __shared__ char kvs[65536];
  __shared__ unsigned short plds[8 * 1152];  // per wave [16][72] padded
  const int tid = threadIdx.x;
  const int wid = tid >> 6, lane = tid & 63;
  const int g = lane >> 4, c = lane & 15;
  const int bc = blockIdx.x;
  const int qt = 7 - blockIdx.y;  // heavy q-tiles dispatch first
  const size_t bcbase = (size_t)bc * TSEQ * DDIM;
  const int qrow = qt * 128 + wid * 16 + c;

  // Q fragments: lane holds Q[q = c (its wave row)][d = ks*32 + g*8 + j]
  bf16x8 qf[16];
  const unsigned short* qp = qkv + bcbase + (size_t)qrow * DDIM + g * 8;
#pragma unroll
  for (int ks = 0; ks < 16; ++ks) qf[ks] = *(const bf16x8*)(qp + ks * 32);

  f32x4 oacc[32] = {};
  float mrun = -1e30f, lrun = 0.0f;
  const float scale = 0.044194173824159216f;  // 512^-0.5

  unsigned short* pbuf = plds + wid * 1152;
  const int nkv = 2 * qt + 2;

  for (int kvt = 0; kvt < nkv; ++kvt) {
    __syncthreads();
    const char* tb = (const char*)(qkv + bcbase + (size_t)kvt * 64 * DDIM);
#pragma unroll
    for (int r = 0; r < 8; ++r)  // contiguous 64KB tile copy, linear LDS
      async_load16(tb + r * 8192 + tid * 16, kvs + r * 8192 + (wid << 10));
    __syncthreads();

    // ---- QK^T (swapped): st[ft] holds S^T[kv = ft*16 + g*4 + r][q = c]
    f32x4 st[4] = {};
#pragma unroll
    for (int ks = 0; ks < 16; ++ks) {
      const int dby = (ks * 32 + g * 8) * 2;
#pragma unroll
      for (int ft = 0; ft < 4; ++ft) {
        const bf16x8 kf = *(const bf16x8*)(kvs + (ft * 16 + c) * 1024 + dby);
        st[ft] = MFMA(kf, qf[ks], st[ft]);
      }
    }

    // ---- online softmax (per lane: q = c, 16 kv values)
    float sv[16];
#pragma unroll
    for (int ft = 0; ft < 4; ++ft) {
#pragma unroll
      for (int r = 0; r < 4; ++r) {
        const float v = st[ft][r] * scale;
        const int kvg = kvt * 64 + ft * 16 + g * 4 + r;
        sv[ft * 4 + r] = (kvg > qrow) ? -1e30f : v;
      }
    }
    float mt = sv[0];
#pragma unroll
    for (int i = 1; i < 16; ++i) mt = fmaxf(mt, sv[i]);
    mt = fmaxf(mt, __shfl_xor(mt, 16));
    mt = fmaxf(mt, __shfl_xor(mt, 32));
    const float mnew = fmaxf(mrun, mt);
    const float corr = __expf(mrun - mnew);
    float psum = 0.0f;
    unsigned int pw[8];
#pragma unroll
    for (int i = 0; i < 8; ++i) {
      const float p0 = __expf(sv[2 * i] - mnew);
      const float p1 = __expf(sv[2 * i + 1] - mnew);
      psum += p0 + p1;
      pw[i] = (unsigned)f2bf(p0) | ((unsigned)f2bf(p1) << 16);
    }
    psum += __shfl_xor(psum, 16);
    psum += __shfl_xor(psum, 32);
    lrun = lrun * corr + psum;
    mrun = mnew;

    // write P to per-wave LDS: row q=c (stride 72), cols ft*16 + g*4 + {0..3}
#pragma unroll
    for (int ft = 0; ft < 4; ++ft) {
      uint2 pk;
      pk.x = pw[2 * ft];
      pk.y = pw[2 * ft + 1];
      *(uint2*)(pbuf + c * 72 + ft * 16 + g * 4) = pk;
    }
    asm volatile("" ::: "memory");
    const bf16x8 pa0 = *(const bf16x8*)(pbuf + c * 72 + g * 8);
    const bf16x8 pa1 = *(const bf16x8*)(pbuf + c * 72 + 32 + g * 8);

    // rescale O by corr (oacc rows are q = g*4 + r)
    float cr[4];
#pragma unroll
    for (int r = 0; r < 4; ++r) cr[r] = __shfl(corr, g * 4 + r);
#pragma unroll
    for (int dt = 0; dt < 32; ++dt) {
      oacc[dt][0] *= cr[0];
      oacc[dt][1] *= cr[1];
      oacc[dt][2] *= cr[2];
      oacc[dt][3] *= cr[3];
    }

    // ---- PV: V fragment B[k=kv][col=d] via strided scalar LDS reads
#pragma unroll
    for (int dt = 0; dt < 32; ++dt) {
      const char* vc = kvs + (dt * 16 + c) * 2;
      bf16x8 b0, b1;
#pragma unroll
      for (int j = 0; j < 8; ++j) {
        b0[j] = *(const short*)(vc + (g * 8 + j) * 1024);
        b1[j] = *(const short*)(vc + (32 + g * 8 + j) * 1024);
      }
      oacc[dt] = MFMA(pa0, b0, oacc[dt]);
      oacc[dt] = MFMA(pa1, b1, oacc[dt]);
    }
  }

  // ---- epilogue: x + O/l
  const float rl = 1.0f / lrun;
  float rlr[4];
#pragma unroll
  for (int r = 0; r < 4; ++r) rlr[r] = __shfl(rl, g * 4 + r);
#pragma unroll
  for (int dt = 0; dt < 32; ++dt) {
#pragma unroll
    for (int r = 0; r < 4; ++r) {
      const size_t off =
          bcbase + (size_t)(qt * 128 + wid * 16 + g * 4 + r) * DDIM + dt * 16 + c;
      xo[off] = x[off] + oacc[dt][r] * rlr[r];
    }
  }
}

// ---------------- cell mixing + sin pulse (in-place on d_out) ----------------
__global__ __launch_bounds__(256) void k_mix(float* __restrict__ xo,
                                             const float* __restrict__ inh,
                                             const float* __restrict__ phz,
                                             const float* __restrict__ rsc) {
  __shared__ float sI[256];
  __shared__ float sP[16];
  const int tid = threadIdx.x;
  sI[tid] = inh[tid];
  if (tid < 16) sP[tid] = phz[tid];
  __syncthreads();
  const float rs = rsc[0];
  const int idx = blockIdx.x * 256 + tid;
  const int d4 = idx & 127;
  const int t = (idx >> 7) & 1023;
  const int b = idx >> 17;
  float4* base = (float4*)xo + ((size_t)b * 16 * TSEQ + t) * 128 + d4;
  float4 v[16];
#pragma unroll
  for (int cc = 0; cc < 16; ++cc) v[cc] = base[(size_t)cc * TSEQ * 128];
#pragma unroll
  for (int k = 0; k < 16; ++k) {
    float4 comp = make_float4(0.f, 0.f, 0.f, 0.f);
#pragma unroll
    for (int cc = 0; cc < 16; ++cc) {
      const float w = sI[cc * 16 + k];
      comp.x += v[cc].x * w;
      comp.y += v[cc].y * w;
      comp.z += v[cc].z * w;
      comp.w += v[cc].w * w;
    }
    const float ph = sP[k];
    float4 o;
    o.x = v[k].x + __sinf(comp.x + ph) * rs;
    o.y = v[k].y + __sinf(comp.y + ph) * rs;
    o.z = v[k].z + __sinf(comp.z + ph) * rs;
    o.w = v[k].w + __sinf(comp.w + ph) * rs;
    base[(size_t)k * TSEQ * 128] = o;
  }
}

extern "C" void kernel_launch(void* const* d_in, const int* in_sizes, int n_in,
                              void* d_out, int out_size, void* d_ws, size_t ws_size,
                              hipStream_t stream) {
  const float* x = (const float*)d_in[0];
  // d_in[1] = mask (causal, strict upper triangle) -- implemented analytically
  const float* gamma = (const float*)d_in[2];
  const float* beta = (const float*)d_in[3];
  const float* Wg = (const float*)d_in[4];
  const float* inh = (const float*)d_in[5];
  const float* phz = (const float*)d_in[6];
  const float* rsc = (const float*)d_in[7];
  float* out = (float*)d_out;

  // workspace: only wgb (0.5 MiB) + qkv (64 MiB). nx lives in d_out (dead
  // before k_attn writes real output there).
  unsigned short* wgb = (unsigned short*)d_ws;
  unsigned short* qkv = wgb + (size_t)262144;
  unsigned short* nx = (unsigned short*)d_out;

  k_cast<<<128, 256, 0, stream>>>(Wg, wgb, 32768);
  k_ln<<<16384, 256, 0, stream>>>(x, gamma, beta, nx);
  k_gemm<<<dim3(4, 512), 256, 0, stream>>>(nx, wgb, qkv);
  k_attn<<<dim3(64, 8), 512, 0, stream>>>(qkv, x, out);
  k_mix<<<2048, 256, 0, stream>>>(out, inh, phz, rsc);
}